// Round 16
// baseline (204.955 us; speedup 1.0000x reference)
//
#include <hip/hip_runtime.h>
#include <hip/hip_fp16.h>

// GCN 2-layer. partition (EPB=4096, 512 thr, LDS-staged coalesced writes) ->
// csr+norms+transform1 fused (1024 thr) + per-bucket degree sort (perm) ->
// gather1 (8 nodes/wave, degree-ordered) -> gather2 (16 nodes/wave).

#define NB   391      // buckets = ceil(100000/256); bucket = id >> 8
#define CAPB 5504     // padded per-bucket edge capacity (avg 4092, +22 sigma)
#define EPB  4096     // edges per partition block (8/thread at 512 threads)
#define NSLOT (NB * 256)

__device__ __forceinline__ long nt_load_i64(const long* p) {
    return __builtin_nontemporal_load(p);
}

// --- pass 1: partition edges by dst-bucket; LDS-staged, coalesced run writes ---
__global__ __launch_bounds__(512) void partition_kernel(
        const int* __restrict__ src, const int* __restrict__ dst,
        const float* __restrict__ ew,
        int* __restrict__ g_cur_d, int* __restrict__ g_cur_s,
        int2* __restrict__ pack_part, unsigned char* __restrict__ src_part, int m) {
    __shared__ int hist_d[NB], hist_s[NB];
    __shared__ int lbase_d[NB], lbase_s[NB];
    __shared__ int gbase_d[NB], gbase_s[NB];
    __shared__ int cur_d[NB], cur_s[NB];
    __shared__ int sc[2][512];
    __shared__ long stage[EPB];            // 32 KB
    __shared__ unsigned short dbuck[EPB];  // 8 KB
    __shared__ unsigned char  sstage[EPB]; // 4 KB
    __shared__ unsigned short sbuck[EPB];  // 8 KB
    int t = threadIdx.x;
    for (int i = t; i < NB; i += 512) {
        hist_d[i] = 0; hist_s[i] = 0; cur_d[i] = 0; cur_s[i] = 0;
    }
    __syncthreads();
    int base_e = blockIdx.x * EPB;
    int total = m - base_e; if (total > EPB) total = EPB;
    int es[8], ed[8]; float wv[8];
#pragma unroll
    for (int k = 0; k < 8; k++) {
        int e = base_e + k * 512 + t;
        if (e < m) { es[k] = src[e]; ed[k] = dst[e]; wv[k] = ew[e]; }
        else ed[k] = -1;
    }
#pragma unroll
    for (int k = 0; k < 8; k++) {
        if (ed[k] >= 0) {
            atomicAdd(&hist_d[ed[k] >> 8], 1);
            atomicAdd(&hist_s[es[k] >> 8], 1);
        }
    }
    __syncthreads();
    if (t < 512) sc[0][t] = (t < NB) ? hist_d[t] : 0;
    __syncthreads();
    int pp = 0;
    for (int off = 1; off < 512; off <<= 1) {
        sc[1 - pp][t] = sc[pp][t] + (t >= off ? sc[pp][t - off] : 0);
        __syncthreads();
        pp ^= 1;
    }
    for (int i = t; i < NB; i += 512) lbase_d[i] = sc[pp][i] - hist_d[i];
    __syncthreads();
    sc[0][t] = (t < NB) ? hist_s[t] : 0;
    __syncthreads();
    pp = 0;
    for (int off = 1; off < 512; off <<= 1) {
        sc[1 - pp][t] = sc[pp][t] + (t >= off ? sc[pp][t - off] : 0);
        __syncthreads();
        pp ^= 1;
    }
    for (int i = t; i < NB; i += 512) lbase_s[i] = sc[pp][i] - hist_s[i];
    __syncthreads();
    for (int i = t; i < NB; i += 512) {
        int c = hist_d[i];
        gbase_d[i] = i * CAPB + (c ? atomicAdd(&g_cur_d[i], c) : 0);
        c = hist_s[i];
        gbase_s[i] = i * CAPB + (c ? atomicAdd(&g_cur_s[i], c) : 0);
    }
    __syncthreads();
#pragma unroll
    for (int k = 0; k < 8; k++) {
        if (ed[k] >= 0) {
            int d = ed[k], s = es[k];
            int bd = d >> 8;
            int r = atomicAdd(&cur_d[bd], 1);
            int pos = lbase_d[bd] + r;
            stage[pos] = (long)(unsigned int)(s | ((d & 255) << 20)) |
                         ((long)__float_as_int(wv[k]) << 32);
            dbuck[pos] = (unsigned short)bd;
            int bs = s >> 8;
            int rs = atomicAdd(&cur_s[bs], 1);
            int ps = lbase_s[bs] + rs;
            sstage[ps] = (unsigned char)(s & 255);
            sbuck[ps] = (unsigned short)bs;
        }
    }
    __syncthreads();
    long* packl = (long*)pack_part;
    for (int i = t; i < total; i += 512) {
        int b = dbuck[i];
        packl[(size_t)gbase_d[b] + (i - lbase_d[b])] = stage[i];
    }
    for (int i = t; i < total; i += 512) {
        int b = sbuck[i];
        src_part[(size_t)gbase_s[b] + (i - lbase_s[b])] = sstage[i];
    }
}

// --- per bucket (1024 threads): dst CSR + both norms + degree-sorted slot map
//     + fused transform1 for this bucket's 256 nodes. ---
__global__ __launch_bounds__(1024) void csr_kernel(
                           const int2* __restrict__ pack_part,
                           const unsigned char* __restrict__ src_part,
                           const int* __restrict__ g_cur_d, const int* __restrict__ g_cur_s,
                           const float* __restrict__ feat, const float* __restrict__ W1,
                           int2* __restrict__ csr, int2* __restrict__ rs_cnt,
                           int* __restrict__ perm,
                           float* __restrict__ norm_src, float* __restrict__ norm_dst,
                           __half* __restrict__ h1, int n) {
    __shared__ int cnt[256];
    __shared__ int rowx[256];
    __shared__ int cur[256];
    __shared__ int cnt_s[256];
    __shared__ float nsrc[256];
    __shared__ float sW1[1024];
    __shared__ int dbin[64], dcur[64], dbase[64];
    extern __shared__ int2 stage[];  // CAPB entries (44 KB), reused as fp32 tile later
    int t = threadIdx.x, b = blockIdx.x;
    if (t < 256) { cnt[t] = 0; cur[t] = 0; cnt_s[t] = 0; }
    if (t >= 256 && t < 320) { dbin[t - 256] = 0; dcur[t - 256] = 0; }
    sW1[t] = W1[t];
    __syncthreads();
    int count = g_cur_d[b]; if (count > CAPB) count = CAPB;
    int count_s = g_cur_s[b]; if (count_s > CAPB) count_s = CAPB;
    const int2* p = pack_part + (size_t)b * CAPB;
    const unsigned char* sp = src_part + (size_t)b * CAPB;
    for (int e = t; e < count; e += 1024) atomicAdd(&cnt[p[e].x >> 20], 1);
    for (int e = t; e < count_s; e += 1024) atomicAdd(&cnt_s[sp[e]], 1);
    __syncthreads();
    if (t < 256) {
        int node = b * 256 + t;
        if (node < n) {
            int cs = cnt_s[t];
            float ns = rsqrtf((float)(cs > 1 ? cs : 1));
            nsrc[t] = ns;
            norm_src[node] = ns;
        } else nsrc[t] = 0.0f;
    }
    int c0 = 0;
    if (t < 256) { c0 = cnt[t]; rowx[t] = c0; }
    __syncthreads();
    for (int off = 1; off < 256; off <<= 1) {
        int v = 0;
        if (t < 256 && t >= off) v = rowx[t - off];
        __syncthreads();
        if (t < 256) rowx[t] += v;
        __syncthreads();
    }
    int excl = 0, bin = 0;
    if (t < 256) {
        excl = rowx[t] - c0;
        rowx[t] = excl;
        bin = c0 < 63 ? c0 : 63;
        atomicAdd(&dbin[bin], 1);    // degree histogram (64 bins)
        int node = b * 256 + t;
        if (node < n) norm_dst[node] = rsqrtf((float)(c0 > 1 ? c0 : 1));
    }
    __syncthreads();
    if (t == 0) {                    // tiny serial scan over 64 bins
        int s = 0;
        for (int i = 0; i < 64; i++) { dbase[i] = s; s += dbin[i]; }
    }
    __syncthreads();
    if (t < 256) {                   // degree-sorted slot assignment
        int rank = dbase[bin] + atomicAdd(&dcur[bin], 1);
        int gpos = b * 256 + rank;
        int node = b * 256 + t;
        rs_cnt[gpos] = make_int2(b * CAPB + excl, c0);
        perm[gpos] = (node < n) ? node : -1;
    }
    __syncthreads();
    for (int e = t; e < count; e += 1024) {
        int2 v = p[e];
        int dl = v.x >> 20;
        int r = atomicAdd(&cur[dl], 1);
        stage[rowx[dl] + r] = make_int2(v.x & 0x1FFFF, v.y);
    }
    __syncthreads();
    int2* outp = csr + (size_t)b * CAPB;
    for (int e = t; e < count; e += 1024) outp[e] = stage[e];
    __syncthreads();
    // fused transform1: reuse stage as float tile sF[256][32] (32 KB)
    float* sF = (float*)stage;
    int node0 = b * 256;
    int lim = n - node0; if (lim > 256) lim = 256; if (lim < 0) lim = 0;
    for (int o = t; o < lim * 32; o += 1024) {
        int i = o >> 5, k = o & 31;
        sF[o] = feat[(size_t)(node0 + i) * 32 + k] * nsrc[i];
    }
    __syncthreads();
    for (int o = t; o < lim * 32; o += 1024) {
        int i = o >> 5, col = o & 31;
        float acc = 0.0f;
#pragma unroll
        for (int k = 0; k < 32; k++) acc += sF[i * 32 + k] * sW1[k * 32 + col];
        h1[(size_t)(node0 + i) * 32 + col] = __float2half(acc);
    }
}

// --- gather1 + fused transform2: 8 nodes per wave, degree-ordered slots ---
__global__ void gather1_fused_kernel(const __half* __restrict__ h1, const int2* __restrict__ csr,
                                     const int2* __restrict__ rs_cnt, const int* __restrict__ perm,
                                     const float* __restrict__ norm_src, const float* __restrict__ norm_dst,
                                     const float* __restrict__ W2, const float* __restrict__ b1,
                                     __half* __restrict__ h2) {
    __shared__ float sW2[32 * 16];
    __shared__ float sB1[32];
    __shared__ float sX[4][8][32];
    int t = threadIdx.x;
    for (int i = t; i < 512; i += 256) sW2[i] = W2[i];
    if (t < 32) sB1[t] = b1[t];
    __syncthreads();
    int w = t >> 6, lane = t & 63;
    int q = lane >> 3;      // sub-node within wave (0..7)
    int dq = lane & 7;      // float2 index (dims 4dq..4dq+3)
    int gid = (blockIdx.x * 4 + w) * 8 + q;
    int pid = (gid < NSLOT) ? perm[gid] : -1;
    bool valid = pid >= 0;
    int2 rc = valid ? rs_cnt[gid] : make_int2(0, 0);
    long base = rc.x;
    int c = rc.y;
    const float2* tv = (const float2*)h1;   // 8 float2 (32 halves) per row
    const long* csrl = (const long*)csr;
    float a00=0,a01=0,a02=0,a03=0, a10=0,a11=0,a12=0,a13=0;
    float a20=0,a21=0,a22=0,a23=0, a30=0,a31=0,a32=0,a33=0;
    int j = 0;
    for (; j + 3 < c; j += 4) {
        long q0 = nt_load_i64(csrl + base + j);
        long q1 = nt_load_i64(csrl + base + j + 1);
        long q2 = nt_load_i64(csrl + base + j + 2);
        long q3 = nt_load_i64(csrl + base + j + 3);
        float2 r0 = tv[(size_t)((int)q0 & 0xFFFFF) * 8 + dq];
        float2 r1 = tv[(size_t)((int)q1 & 0xFFFFF) * 8 + dq];
        float2 r2 = tv[(size_t)((int)q2 & 0xFFFFF) * 8 + dq];
        float2 r3 = tv[(size_t)((int)q3 & 0xFFFFF) * 8 + dq];
        float w0 = __int_as_float((int)(q0 >> 32)), w1 = __int_as_float((int)(q1 >> 32));
        float w2 = __int_as_float((int)(q2 >> 32)), w3 = __int_as_float((int)(q3 >> 32));
        float2 l0 = __half22float2(*(__half2*)&r0.x), h0 = __half22float2(*(__half2*)&r0.y);
        float2 l1 = __half22float2(*(__half2*)&r1.x), h1v = __half22float2(*(__half2*)&r1.y);
        float2 l2 = __half22float2(*(__half2*)&r2.x), h2v = __half22float2(*(__half2*)&r2.y);
        float2 l3 = __half22float2(*(__half2*)&r3.x), h3v = __half22float2(*(__half2*)&r3.y);
        a00 += l0.x * w0; a01 += l0.y * w0; a02 += h0.x * w0; a03 += h0.y * w0;
        a10 += l1.x * w1; a11 += l1.y * w1; a12 += h1v.x * w1; a13 += h1v.y * w1;
        a20 += l2.x * w2; a21 += l2.y * w2; a22 += h2v.x * w2; a23 += h2v.y * w2;
        a30 += l3.x * w3; a31 += l3.y * w3; a32 += h3v.x * w3; a33 += h3v.y * w3;
    }
    for (; j < c; j++) {
        long qq = nt_load_i64(csrl + base + j);
        float2 r = tv[(size_t)((int)qq & 0xFFFFF) * 8 + dq];
        float ww = __int_as_float((int)(qq >> 32));
        float2 l = __half22float2(*(__half2*)&r.x), h = __half22float2(*(__half2*)&r.y);
        a00 += l.x * ww; a01 += l.y * ww; a02 += h.x * ww; a03 += h.y * ww;
    }
    float s0 = (a00 + a10) + (a20 + a30);
    float s1 = (a01 + a11) + (a21 + a31);
    float s2 = (a02 + a12) + (a22 + a32);
    float s3 = (a03 + a13) + (a23 + a33);
    if (valid) {
        float nd = norm_dst[pid], ns = norm_src[pid];
        int d0 = 4 * dq;
        sX[w][q][d0]     = fmaxf(s0 * nd + sB1[d0],     0.0f) * ns;
        sX[w][q][d0 + 1] = fmaxf(s1 * nd + sB1[d0 + 1], 0.0f) * ns;
        sX[w][q][d0 + 2] = fmaxf(s2 * nd + sB1[d0 + 2], 0.0f) * ns;
        sX[w][q][d0 + 3] = fmaxf(s3 * nd + sB1[d0 + 3], 0.0f) * ns;
    }
    if (valid) {
        float o0 = 0.0f, o1 = 0.0f;
        int c0 = 2 * dq, c1 = 2 * dq + 1;
#pragma unroll
        for (int k = 0; k < 32; k++) {
            float x = sX[w][q][k];
            o0 += x * sW2[k * 16 + c0];
            o1 += x * sW2[k * 16 + c1];
        }
        ((__half2*)h2)[(size_t)pid * 8 + dq] = __floats2half2_rn(o0, o1);
    }
}

// --- gather2 + fused epilogue: 16 nodes per wave, degree-ordered slots ---
__global__ void gather2_kernel(const __half* __restrict__ h2, const int2* __restrict__ csr,
                               const int2* __restrict__ rs_cnt, const int* __restrict__ perm,
                               const float* __restrict__ norm_dst, const float* __restrict__ b2,
                               float* __restrict__ out) {
    int t = threadIdx.x;
    int w = t >> 6, lane = t & 63;
    int q = lane >> 2;     // sub-node within wave (0..15)
    int dq = lane & 3;     // float2 index (dims 4dq..4dq+3)
    int gid = (blockIdx.x * 4 + w) * 16 + q;
    int pid = (gid < NSLOT) ? perm[gid] : -1;
    bool valid = pid >= 0;
    int2 rc = valid ? rs_cnt[gid] : make_int2(0, 0);
    long base = rc.x;
    int c = rc.y;
    const float2* tv = (const float2*)h2;   // 4 float2 (16 halves) per row
    const long* csrl = (const long*)csr;
    float a00=0,a01=0,a02=0,a03=0, a10=0,a11=0,a12=0,a13=0;
    float a20=0,a21=0,a22=0,a23=0, a30=0,a31=0,a32=0,a33=0;
    int j = 0;
    for (; j + 3 < c; j += 4) {
        long q0 = nt_load_i64(csrl + base + j);
        long q1 = nt_load_i64(csrl + base + j + 1);
        long q2 = nt_load_i64(csrl + base + j + 2);
        long q3 = nt_load_i64(csrl + base + j + 3);
        float2 r0 = tv[(size_t)((int)q0 & 0xFFFFF) * 4 + dq];
        float2 r1 = tv[(size_t)((int)q1 & 0xFFFFF) * 4 + dq];
        float2 r2 = tv[(size_t)((int)q2 & 0xFFFFF) * 4 + dq];
        float2 r3 = tv[(size_t)((int)q3 & 0xFFFFF) * 4 + dq];
        float w0 = __int_as_float((int)(q0 >> 32)), w1 = __int_as_float((int)(q1 >> 32));
        float w2 = __int_as_float((int)(q2 >> 32)), w3 = __int_as_float((int)(q3 >> 32));
        float2 l0 = __half22float2(*(__half2*)&r0.x), h0 = __half22float2(*(__half2*)&r0.y);
        float2 l1 = __half22float2(*(__half2*)&r1.x), h1v = __half22float2(*(__half2*)&r1.y);
        float2 l2 = __half22float2(*(__half2*)&r2.x), h2v = __half22float2(*(__half2*)&r2.y);
        float2 l3 = __half22float2(*(__half2*)&r3.x), h3v = __half22float2(*(__half2*)&r3.y);
        a00 += l0.x * w0; a01 += l0.y * w0; a02 += h0.x * w0; a03 += h0.y * w0;
        a10 += l1.x * w1; a11 += l1.y * w1; a12 += h1v.x * w1; a13 += h1v.y * w1;
        a20 += l2.x * w2; a21 += l2.y * w2; a22 += h2v.x * w2; a23 += h2v.y * w2;
        a30 += l3.x * w3; a31 += l3.y * w3; a32 += h3v.x * w3; a33 += h3v.y * w3;
    }
    for (; j < c; j++) {
        long qq = nt_load_i64(csrl + base + j);
        float2 r = tv[(size_t)((int)qq & 0xFFFFF) * 4 + dq];
        float ww = __int_as_float((int)(qq >> 32));
        float2 l = __half22float2(*(__half2*)&r.x), h = __half22float2(*(__half2*)&r.y);
        a00 += l.x * ww; a01 += l.y * ww; a02 += h.x * ww; a03 += h.y * ww;
    }
    if (valid) {
        float nd = norm_dst[pid];
        int d0 = 4 * dq;
        float4 o;
        o.x = ((a00 + a10) + (a20 + a30)) * nd + b2[d0];
        o.y = ((a01 + a11) + (a21 + a31)) * nd + b2[d0 + 1];
        o.z = ((a02 + a12) + (a22 + a32)) * nd + b2[d0 + 2];
        o.w = ((a03 + a13) + (a23 + a33)) * nd + b2[d0 + 3];
        ((float4*)out)[(size_t)pid * 4 + dq] = o;
    }
}

extern "C" void kernel_launch(void* const* d_in, const int* in_sizes, int n_in,
                              void* d_out, int out_size, void* d_ws, size_t ws_size,
                              hipStream_t stream) {
    const float* feat = (const float*)d_in[0];
    const int*   src  = (const int*)d_in[1];
    const int*   dst  = (const int*)d_in[2];
    const float* ew   = (const float*)d_in[3];
    const float* W1   = (const float*)d_in[4];
    const float* b1   = (const float*)d_in[5];
    const float* W2   = (const float*)d_in[6];
    const float* b2   = (const float*)d_in[7];
    float* out = (float*)d_out;

    const int n = in_sizes[0] / 32;  // 100000
    const int m = in_sizes[1];       // 1600000

    // ws: pack_part[NB*CAPB int2] | csr[NB*CAPB int2] | h1 half[32n] | h2 half[16n] |
    //     norm_src[n] | norm_dst[n] | rs_cnt int2[NSLOT] | perm int[NSLOT] |
    //     g_cur_d[NB] | g_cur_s[NB] | src_part uchar[NB*CAPB]
    char* wsb = (char*)d_ws;
    int2*   pack_part = (int2*)wsb;
    int2*   csr       = pack_part + (size_t)NB * CAPB;
    __half* h1        = (__half*)(csr + (size_t)NB * CAPB);
    __half* h2        = h1 + 32 * (size_t)n;
    float*  norm_src  = (float*)(h2 + 16 * (size_t)n);
    float*  norm_dst  = norm_src + n;
    int2*   rs_cnt    = (int2*)(norm_dst + n);
    int*    perm      = (int*)(rs_cnt + NSLOT);
    int*    g_cur_d   = perm + NSLOT;
    int*    g_cur_s   = g_cur_d + NB;
    unsigned char* src_part = (unsigned char*)(g_cur_s + NB);

    hipMemsetAsync(g_cur_d, 0, 2 * NB * sizeof(int), stream);

    partition_kernel<<<(m + EPB - 1) / EPB, 512, 0, stream>>>(src, dst, ew, g_cur_d, g_cur_s,
                                                              pack_part, src_part, m);
    csr_kernel<<<NB, 1024, CAPB * sizeof(int2), stream>>>(pack_part, src_part, g_cur_d, g_cur_s,
                                                          feat, W1, csr, rs_cnt, perm,
                                                          norm_src, norm_dst, h1, n);
    gather1_fused_kernel<<<(NSLOT + 31) / 32, 256, 0, stream>>>(h1, csr, rs_cnt, perm,
                                                                norm_src, norm_dst, W2, b1, h2);
    gather2_kernel<<<(NSLOT + 63) / 64, 256, 0, stream>>>(h2, csr, rs_cnt, perm,
                                                          norm_dst, b2, out);
}

// Round 17
// 188.250 us; speedup vs baseline: 1.0887x; 1.0887x over previous
//
#include <hip/hip_runtime.h>
#include <hip/hip_fp16.h>

// GCN 2-layer — R15 champion (185us), reverted after R16 degree-sort regression.
// partition (EPB=4096, 512 thr, LDS-staged coalesced writes) ->
// csr+norms+transform1 fused (1024 thr) -> gather1 (8 nodes/wave, float2 lanes)
// -> gather2 (16 nodes/wave, float2 lanes, float4 store). fp16 hidden states.

#define NB   391      // buckets = ceil(100000/256); bucket = id >> 8
#define CAPB 5504     // padded per-bucket edge capacity (avg 4092, +22 sigma)
#define EPB  4096     // edges per partition block (8/thread at 512 threads)

__device__ __forceinline__ long nt_load_i64(const long* p) {
    return __builtin_nontemporal_load(p);
}

// --- pass 1: partition edges by dst-bucket; LDS-staged, coalesced run writes ---
__global__ __launch_bounds__(512) void partition_kernel(
        const int* __restrict__ src, const int* __restrict__ dst,
        const float* __restrict__ ew,
        int* __restrict__ g_cur_d, int* __restrict__ g_cur_s,
        int2* __restrict__ pack_part, unsigned char* __restrict__ src_part, int m) {
    __shared__ int hist_d[NB], hist_s[NB];
    __shared__ int lbase_d[NB], lbase_s[NB];
    __shared__ int gbase_d[NB], gbase_s[NB];
    __shared__ int cur_d[NB], cur_s[NB];
    __shared__ int sc[2][512];
    __shared__ long stage[EPB];            // 32 KB
    __shared__ unsigned short dbuck[EPB];  // 8 KB
    __shared__ unsigned char  sstage[EPB]; // 4 KB
    __shared__ unsigned short sbuck[EPB];  // 8 KB
    int t = threadIdx.x;
    for (int i = t; i < NB; i += 512) {
        hist_d[i] = 0; hist_s[i] = 0; cur_d[i] = 0; cur_s[i] = 0;
    }
    __syncthreads();
    int base_e = blockIdx.x * EPB;
    int total = m - base_e; if (total > EPB) total = EPB;
    int es[8], ed[8]; float wv[8];
#pragma unroll
    for (int k = 0; k < 8; k++) {
        int e = base_e + k * 512 + t;
        if (e < m) { es[k] = src[e]; ed[k] = dst[e]; wv[k] = ew[e]; }
        else ed[k] = -1;
    }
#pragma unroll
    for (int k = 0; k < 8; k++) {
        if (ed[k] >= 0) {
            atomicAdd(&hist_d[ed[k] >> 8], 1);
            atomicAdd(&hist_s[es[k] >> 8], 1);
        }
    }
    __syncthreads();
    if (t < 512) sc[0][t] = (t < NB) ? hist_d[t] : 0;
    __syncthreads();
    int pp = 0;
    for (int off = 1; off < 512; off <<= 1) {
        sc[1 - pp][t] = sc[pp][t] + (t >= off ? sc[pp][t - off] : 0);
        __syncthreads();
        pp ^= 1;
    }
    for (int i = t; i < NB; i += 512) lbase_d[i] = sc[pp][i] - hist_d[i];
    __syncthreads();
    sc[0][t] = (t < NB) ? hist_s[t] : 0;
    __syncthreads();
    pp = 0;
    for (int off = 1; off < 512; off <<= 1) {
        sc[1 - pp][t] = sc[pp][t] + (t >= off ? sc[pp][t - off] : 0);
        __syncthreads();
        pp ^= 1;
    }
    for (int i = t; i < NB; i += 512) lbase_s[i] = sc[pp][i] - hist_s[i];
    __syncthreads();
    for (int i = t; i < NB; i += 512) {
        int c = hist_d[i];
        gbase_d[i] = i * CAPB + (c ? atomicAdd(&g_cur_d[i], c) : 0);
        c = hist_s[i];
        gbase_s[i] = i * CAPB + (c ? atomicAdd(&g_cur_s[i], c) : 0);
    }
    __syncthreads();
#pragma unroll
    for (int k = 0; k < 8; k++) {
        if (ed[k] >= 0) {
            int d = ed[k], s = es[k];
            int bd = d >> 8;
            int r = atomicAdd(&cur_d[bd], 1);
            int pos = lbase_d[bd] + r;
            stage[pos] = (long)(unsigned int)(s | ((d & 255) << 20)) |
                         ((long)__float_as_int(wv[k]) << 32);
            dbuck[pos] = (unsigned short)bd;
            int bs = s >> 8;
            int rs = atomicAdd(&cur_s[bs], 1);
            int ps = lbase_s[bs] + rs;
            sstage[ps] = (unsigned char)(s & 255);
            sbuck[ps] = (unsigned short)bs;
        }
    }
    __syncthreads();
    long* packl = (long*)pack_part;
    for (int i = t; i < total; i += 512) {
        int b = dbuck[i];
        packl[(size_t)gbase_d[b] + (i - lbase_d[b])] = stage[i];
    }
    for (int i = t; i < total; i += 512) {
        int b = sbuck[i];
        src_part[(size_t)gbase_s[b] + (i - lbase_s[b])] = sstage[i];
    }
}

// --- per bucket (1024 threads): dst CSR (hist+scan+scatter in LDS) + both norms
//     + fused transform1 for this bucket's 256 nodes (h1 = feat*ns @ W1). ---
__global__ __launch_bounds__(1024) void csr_kernel(
                           const int2* __restrict__ pack_part,
                           const unsigned char* __restrict__ src_part,
                           const int* __restrict__ g_cur_d, const int* __restrict__ g_cur_s,
                           const float* __restrict__ feat, const float* __restrict__ W1,
                           int2* __restrict__ csr, int2* __restrict__ rs_cnt,
                           float* __restrict__ norm_src, float* __restrict__ norm_dst,
                           __half* __restrict__ h1, int n) {
    __shared__ int cnt[256];
    __shared__ int rowx[256];
    __shared__ int cur[256];
    __shared__ int cnt_s[256];
    __shared__ float nsrc[256];
    __shared__ float sW1[1024];
    extern __shared__ int2 stage[];  // CAPB entries (44 KB), reused as fp32 tile later
    int t = threadIdx.x, b = blockIdx.x;
    if (t < 256) { cnt[t] = 0; cur[t] = 0; cnt_s[t] = 0; }
    sW1[t] = W1[t];
    __syncthreads();
    int count = g_cur_d[b]; if (count > CAPB) count = CAPB;
    int count_s = g_cur_s[b]; if (count_s > CAPB) count_s = CAPB;
    const int2* p = pack_part + (size_t)b * CAPB;
    const unsigned char* sp = src_part + (size_t)b * CAPB;
    for (int e = t; e < count; e += 1024) atomicAdd(&cnt[p[e].x >> 20], 1);
    for (int e = t; e < count_s; e += 1024) atomicAdd(&cnt_s[sp[e]], 1);
    __syncthreads();
    if (t < 256) {
        int node = b * 256 + t;
        if (node < n) {
            int cs = cnt_s[t];
            float ns = rsqrtf((float)(cs > 1 ? cs : 1));
            nsrc[t] = ns;
            norm_src[node] = ns;
        } else nsrc[t] = 0.0f;
    }
    int c0 = 0;
    if (t < 256) { c0 = cnt[t]; rowx[t] = c0; }
    __syncthreads();
    for (int off = 1; off < 256; off <<= 1) {
        int v = 0;
        if (t < 256 && t >= off) v = rowx[t - off];
        __syncthreads();
        if (t < 256) rowx[t] += v;
        __syncthreads();
    }
    if (t < 256) {
        int excl = rowx[t] - c0;
        rowx[t] = excl;
        int node = b * 256 + t;
        if (node < n) {
            rs_cnt[node] = make_int2(b * CAPB + excl, c0);
            norm_dst[node] = rsqrtf((float)(c0 > 1 ? c0 : 1));
        }
    }
    __syncthreads();
    for (int e = t; e < count; e += 1024) {
        int2 v = p[e];
        int dl = v.x >> 20;
        int r = atomicAdd(&cur[dl], 1);
        stage[rowx[dl] + r] = make_int2(v.x & 0x1FFFF, v.y);
    }
    __syncthreads();
    int2* outp = csr + (size_t)b * CAPB;
    for (int e = t; e < count; e += 1024) outp[e] = stage[e];
    __syncthreads();
    // fused transform1: reuse stage as float tile sF[256][32] (32 KB)
    float* sF = (float*)stage;
    int node0 = b * 256;
    int lim = n - node0; if (lim > 256) lim = 256; if (lim < 0) lim = 0;
    for (int o = t; o < lim * 32; o += 1024) {
        int i = o >> 5, k = o & 31;
        sF[o] = feat[(size_t)(node0 + i) * 32 + k] * nsrc[i];
    }
    __syncthreads();
    for (int o = t; o < lim * 32; o += 1024) {
        int i = o >> 5, col = o & 31;
        float acc = 0.0f;
#pragma unroll
        for (int k = 0; k < 32; k++) acc += sF[i * 32 + k] * sW1[k * 32 + col];
        h1[(size_t)(node0 + i) * 32 + col] = __float2half(acc);
    }
}

// --- gather1 + fused transform2: 8 nodes per wave (8 lanes each, lane owns
//     4 dims via one float2(=2xhalf2) load) -> 32 indep chains/wave. ---
__global__ void gather1_fused_kernel(const __half* __restrict__ h1, const int2* __restrict__ csr,
                                     const int2* __restrict__ rs_cnt,
                                     const float* __restrict__ norm_src, const float* __restrict__ norm_dst,
                                     const float* __restrict__ W2, const float* __restrict__ b1,
                                     __half* __restrict__ h2, int n) {
    __shared__ float sW2[32 * 16];
    __shared__ float sB1[32];
    __shared__ float sX[4][8][32];
    int t = threadIdx.x;
    for (int i = t; i < 512; i += 256) sW2[i] = W2[i];
    if (t < 32) sB1[t] = b1[t];
    __syncthreads();
    int w = t >> 6, lane = t & 63;
    int q = lane >> 3;      // sub-node within wave (0..7)
    int dq = lane & 7;      // float2 index (dims 4dq..4dq+3)
    int node = (blockIdx.x * 4 + w) * 8 + q;
    bool valid = node < n;
    int2 rc = valid ? rs_cnt[node] : make_int2(0, 0);
    long base = rc.x;
    int c = rc.y;
    const float2* tv = (const float2*)h1;   // 8 float2 (32 halves) per row
    const long* csrl = (const long*)csr;
    float a00=0,a01=0,a02=0,a03=0, a10=0,a11=0,a12=0,a13=0;
    float a20=0,a21=0,a22=0,a23=0, a30=0,a31=0,a32=0,a33=0;
    int j = 0;
    for (; j + 3 < c; j += 4) {
        long q0 = nt_load_i64(csrl + base + j);
        long q1 = nt_load_i64(csrl + base + j + 1);
        long q2 = nt_load_i64(csrl + base + j + 2);
        long q3 = nt_load_i64(csrl + base + j + 3);
        float2 r0 = tv[(size_t)((int)q0 & 0xFFFFF) * 8 + dq];
        float2 r1 = tv[(size_t)((int)q1 & 0xFFFFF) * 8 + dq];
        float2 r2 = tv[(size_t)((int)q2 & 0xFFFFF) * 8 + dq];
        float2 r3 = tv[(size_t)((int)q3 & 0xFFFFF) * 8 + dq];
        float w0 = __int_as_float((int)(q0 >> 32)), w1 = __int_as_float((int)(q1 >> 32));
        float w2 = __int_as_float((int)(q2 >> 32)), w3 = __int_as_float((int)(q3 >> 32));
        float2 l0 = __half22float2(*(__half2*)&r0.x), h0 = __half22float2(*(__half2*)&r0.y);
        float2 l1 = __half22float2(*(__half2*)&r1.x), h1v = __half22float2(*(__half2*)&r1.y);
        float2 l2 = __half22float2(*(__half2*)&r2.x), h2v = __half22float2(*(__half2*)&r2.y);
        float2 l3 = __half22float2(*(__half2*)&r3.x), h3v = __half22float2(*(__half2*)&r3.y);
        a00 += l0.x * w0; a01 += l0.y * w0; a02 += h0.x * w0; a03 += h0.y * w0;
        a10 += l1.x * w1; a11 += l1.y * w1; a12 += h1v.x * w1; a13 += h1v.y * w1;
        a20 += l2.x * w2; a21 += l2.y * w2; a22 += h2v.x * w2; a23 += h2v.y * w2;
        a30 += l3.x * w3; a31 += l3.y * w3; a32 += h3v.x * w3; a33 += h3v.y * w3;
    }
    for (; j < c; j++) {
        long qq = nt_load_i64(csrl + base + j);
        float2 r = tv[(size_t)((int)qq & 0xFFFFF) * 8 + dq];
        float ww = __int_as_float((int)(qq >> 32));
        float2 l = __half22float2(*(__half2*)&r.x), h = __half22float2(*(__half2*)&r.y);
        a00 += l.x * ww; a01 += l.y * ww; a02 += h.x * ww; a03 += h.y * ww;
    }
    float s0 = (a00 + a10) + (a20 + a30);
    float s1 = (a01 + a11) + (a21 + a31);
    float s2 = (a02 + a12) + (a22 + a32);
    float s3 = (a03 + a13) + (a23 + a33);
    if (valid) {
        float nd = norm_dst[node], ns = norm_src[node];
        int d0 = 4 * dq;
        sX[w][q][d0]     = fmaxf(s0 * nd + sB1[d0],     0.0f) * ns;
        sX[w][q][d0 + 1] = fmaxf(s1 * nd + sB1[d0 + 1], 0.0f) * ns;
        sX[w][q][d0 + 2] = fmaxf(s2 * nd + sB1[d0 + 2], 0.0f) * ns;
        sX[w][q][d0 + 3] = fmaxf(s3 * nd + sB1[d0 + 3], 0.0f) * ns;
    }
    // wave-synchronous LDS use (same wave wrote sX[w][q]); lane computes 2 cols
    if (valid) {
        float o0 = 0.0f, o1 = 0.0f;
        int c0 = 2 * dq, c1 = 2 * dq + 1;
#pragma unroll
        for (int k = 0; k < 32; k++) {
            float x = sX[w][q][k];
            o0 += x * sW2[k * 16 + c0];
            o1 += x * sW2[k * 16 + c1];
        }
        ((__half2*)h2)[(size_t)node * 8 + dq] = __floats2half2_rn(o0, o1);
    }
}

// --- gather2 + fused epilogue: 16 nodes per wave (4 lanes each, lane owns
//     4 dims via one float2 load) -> float4 store, no LDS. ---
__global__ void gather2_kernel(const __half* __restrict__ h2, const int2* __restrict__ csr,
                               const int2* __restrict__ rs_cnt,
                               const float* __restrict__ norm_dst, const float* __restrict__ b2,
                               float* __restrict__ out, int n) {
    int t = threadIdx.x;
    int w = t >> 6, lane = t & 63;
    int q = lane >> 2;     // sub-node within wave (0..15)
    int dq = lane & 3;     // float2 index (dims 4dq..4dq+3)
    int node = (blockIdx.x * 4 + w) * 16 + q;
    bool valid = node < n;
    int2 rc = valid ? rs_cnt[node] : make_int2(0, 0);
    long base = rc.x;
    int c = rc.y;
    const float2* tv = (const float2*)h2;   // 4 float2 (16 halves) per row
    const long* csrl = (const long*)csr;
    float a00=0,a01=0,a02=0,a03=0, a10=0,a11=0,a12=0,a13=0;
    float a20=0,a21=0,a22=0,a23=0, a30=0,a31=0,a32=0,a33=0;
    int j = 0;
    for (; j + 3 < c; j += 4) {
        long q0 = nt_load_i64(csrl + base + j);
        long q1 = nt_load_i64(csrl + base + j + 1);
        long q2 = nt_load_i64(csrl + base + j + 2);
        long q3 = nt_load_i64(csrl + base + j + 3);
        float2 r0 = tv[(size_t)((int)q0 & 0xFFFFF) * 4 + dq];
        float2 r1 = tv[(size_t)((int)q1 & 0xFFFFF) * 4 + dq];
        float2 r2 = tv[(size_t)((int)q2 & 0xFFFFF) * 4 + dq];
        float2 r3 = tv[(size_t)((int)q3 & 0xFFFFF) * 4 + dq];
        float w0 = __int_as_float((int)(q0 >> 32)), w1 = __int_as_float((int)(q1 >> 32));
        float w2 = __int_as_float((int)(q2 >> 32)), w3 = __int_as_float((int)(q3 >> 32));
        float2 l0 = __half22float2(*(__half2*)&r0.x), h0 = __half22float2(*(__half2*)&r0.y);
        float2 l1 = __half22float2(*(__half2*)&r1.x), h1v = __half22float2(*(__half2*)&r1.y);
        float2 l2 = __half22float2(*(__half2*)&r2.x), h2v = __half22float2(*(__half2*)&r2.y);
        float2 l3 = __half22float2(*(__half2*)&r3.x), h3v = __half22float2(*(__half2*)&r3.y);
        a00 += l0.x * w0; a01 += l0.y * w0; a02 += h0.x * w0; a03 += h0.y * w0;
        a10 += l1.x * w1; a11 += l1.y * w1; a12 += h1v.x * w1; a13 += h1v.y * w1;
        a20 += l2.x * w2; a21 += l2.y * w2; a22 += h2v.x * w2; a23 += h2v.y * w2;
        a30 += l3.x * w3; a31 += l3.y * w3; a32 += h3v.x * w3; a33 += h3v.y * w3;
    }
    for (; j < c; j++) {
        long qq = nt_load_i64(csrl + base + j);
        float2 r = tv[(size_t)((int)qq & 0xFFFFF) * 4 + dq];
        float ww = __int_as_float((int)(qq >> 32));
        float2 l = __half22float2(*(__half2*)&r.x), h = __half22float2(*(__half2*)&r.y);
        a00 += l.x * ww; a01 += l.y * ww; a02 += h.x * ww; a03 += h.y * ww;
    }
    if (valid) {
        float nd = norm_dst[node];
        int d0 = 4 * dq;
        float4 o;
        o.x = ((a00 + a10) + (a20 + a30)) * nd + b2[d0];
        o.y = ((a01 + a11) + (a21 + a31)) * nd + b2[d0 + 1];
        o.z = ((a02 + a12) + (a22 + a32)) * nd + b2[d0 + 2];
        o.w = ((a03 + a13) + (a23 + a33)) * nd + b2[d0 + 3];
        ((float4*)out)[(size_t)node * 4 + dq] = o;
    }
}

extern "C" void kernel_launch(void* const* d_in, const int* in_sizes, int n_in,
                              void* d_out, int out_size, void* d_ws, size_t ws_size,
                              hipStream_t stream) {
    const float* feat = (const float*)d_in[0];
    const int*   src  = (const int*)d_in[1];
    const int*   dst  = (const int*)d_in[2];
    const float* ew   = (const float*)d_in[3];
    const float* W1   = (const float*)d_in[4];
    const float* b1   = (const float*)d_in[5];
    const float* W2   = (const float*)d_in[6];
    const float* b2   = (const float*)d_in[7];
    float* out = (float*)d_out;

    const int n = in_sizes[0] / 32;  // 100000
    const int m = in_sizes[1];       // 1600000

    // ws: pack_part[NB*CAPB int2] | csr[NB*CAPB int2] | h1 half[32n] | h2 half[16n] |
    //     norm_src[n] | norm_dst[n] | rs_cnt int2[n] | g_cur_d[NB] | g_cur_s[NB] |
    //     src_part uchar[NB*CAPB]
    char* wsb = (char*)d_ws;
    int2*   pack_part = (int2*)wsb;
    int2*   csr       = pack_part + (size_t)NB * CAPB;
    __half* h1        = (__half*)(csr + (size_t)NB * CAPB);
    __half* h2        = h1 + 32 * (size_t)n;
    float*  norm_src  = (float*)(h2 + 16 * (size_t)n);
    float*  norm_dst  = norm_src + n;
    int2*   rs_cnt    = (int2*)(norm_dst + n);
    int*    g_cur_d   = (int*)(rs_cnt + n);
    int*    g_cur_s   = g_cur_d + NB;
    unsigned char* src_part = (unsigned char*)(g_cur_s + NB);

    hipMemsetAsync(g_cur_d, 0, 2 * NB * sizeof(int), stream);

    partition_kernel<<<(m + EPB - 1) / EPB, 512, 0, stream>>>(src, dst, ew, g_cur_d, g_cur_s,
                                                              pack_part, src_part, m);
    csr_kernel<<<NB, 1024, CAPB * sizeof(int2), stream>>>(pack_part, src_part, g_cur_d, g_cur_s,
                                                          feat, W1, csr, rs_cnt,
                                                          norm_src, norm_dst, h1, n);
    gather1_fused_kernel<<<(n + 31) / 32, 256, 0, stream>>>(h1, csr, rs_cnt,
                                                            norm_src, norm_dst, W2, b1, h2, n);
    gather2_kernel<<<(n + 63) / 64, 256, 0, stream>>>(h2, csr, rs_cnt, norm_dst, b2, out, n);
}